// Round 10
// baseline (773.416 us; speedup 1.0000x reference)
//
#include <hip/hip_runtime.h>
#include <hip/hip_bf16.h>

#define DDIM    128
#define NPAIRS  8128
#define NROWS   131072
#define NCHUNK  16
#define CPAIRS  (NPAIRS / NCHUNK)   // 508 pairs per chunk
#define MATELEM 16384               // elements per plane (128x128)
#define MSTRIDE (2 * MATELEM)       // planes per slot: hi, lo (A-role or B-role)
#define SLOT_L0 16                  // slots 16..19: level-0 fan4 outputs
#define SLOT_R  20                  // slot 20: final R (B-role)
#define NGEMMB  2048                // 2048 x 64 rows
#define NBUILDB 32                  // 16 chunks x 2 row-halves

typedef __attribute__((ext_vector_type(8))) short bf16x8;
typedef __attribute__((ext_vector_type(4))) float f32x4;
typedef __attribute__((ext_vector_type(4))) unsigned short u16x4;

// Fragment layouts for mfma_f32_16x16x32_bf16 (verified m89 mapping):
//  A-plane: M[row][k] at ((row>>4)*4 + (k>>5))*512 + ((((k>>3)&3)*16 + (row&15))*8) + (k&7)
//  B-plane: M[k][col] at ((col>>4)*4 + (k>>5))*512 + ((((k>>3)&3)*16 + (col&15))*8) + (k&7)
// -> per-lane loads are contiguous 16B.

__device__ inline unsigned short f32_to_bf16_rne(float f) {
    unsigned u = __float_as_uint(f);
    u += 0x7fffu + ((u >> 16) & 1u);
    return (unsigned short)(u >> 16);
}
__device__ inline float bf16_to_f32(unsigned short h) {
    return __uint_as_float((unsigned)h << 16);
}
__device__ inline void bsplit(float v, unsigned short& hi, unsigned short& lo) {
    hi = f32_to_bf16_rne(v);
    lo = f32_to_bf16_rne(v - bf16_to_f32(hi));
}

__device__ inline void waitflag_fast(int* f) {
    while (__hip_atomic_load(f, __ATOMIC_ACQUIRE, __HIP_MEMORY_SCOPE_AGENT) == 0)
        __builtin_amdgcn_s_sleep(2);
}
__device__ inline void waitflag_slow(int* f) {
    while (__hip_atomic_load(f, __ATOMIC_ACQUIRE, __HIP_MEMORY_SCOPE_AGENT) == 0)
        __builtin_amdgcn_s_sleep(32);
}
__device__ inline void setflag(int* f) {
    __hip_atomic_store(f, 1, __ATOMIC_RELEASE, __HIP_MEMORY_SCOPE_AGENT);
}

// ---------------------------------------------------------------------------
// fan4: P = s0 . s1 . s2 . s3 (s0 = A-role planes, s1..3 = B-role planes),
// written OUT-OF-PLACE to D (A-role if as_a else B-role). 4 waves; each wave
// processes mtiles {wave, wave+4} sequentially (halves), intermediate T = f32
// in LDS, wave-local 16 rows -> no barriers. Split precision: 3 MFMAs/frag.
// ---------------------------------------------------------------------------
__device__ void fan4(const unsigned short* __restrict__ s0,
                     const unsigned short* __restrict__ s1,
                     const unsigned short* __restrict__ s2,
                     const unsigned short* __restrict__ s3,
                     unsigned short* __restrict__ D, bool as_a,
                     float* __restrict__ T /* 64 x 132 f32 */) {
    const int lane = threadIdx.x & 63;
    const int wave = threadIdx.x >> 6;   // 0..3
    const int lrow = lane & 15;
    const int lkhi = lane >> 4;

    #pragma unroll 1
    for (int half = 0; half < 2; ++half) {
        const int mt = wave + half * 4;
        f32x4 acc[8];

        // ---- step 0: acc = frag(s0, mt) x s1
        #pragma unroll
        for (int n = 0; n < 8; ++n) acc[n] = (f32x4){0.f, 0.f, 0.f, 0.f};
        #pragma unroll
        for (int ks = 0; ks < 4; ++ks) {
            const unsigned short* ap = s0 + ((size_t)(mt * 4 + ks) * 64 + lane) * 8;
            bf16x8 ahi = *reinterpret_cast<const bf16x8*>(ap);
            bf16x8 alo = *reinterpret_cast<const bf16x8*>(ap + MATELEM);
            #pragma unroll
            for (int n = 0; n < 8; ++n) {
                const unsigned short* bp = s1 + ((size_t)(n * 4 + ks) * 64 + lane) * 8;
                bf16x8 bhi = *reinterpret_cast<const bf16x8*>(bp);
                bf16x8 blo = *reinterpret_cast<const bf16x8*>(bp + MATELEM);
                acc[n] = __builtin_amdgcn_mfma_f32_16x16x32_bf16(ahi, bhi, acc[n], 0, 0, 0);
                acc[n] = __builtin_amdgcn_mfma_f32_16x16x32_bf16(alo, bhi, acc[n], 0, 0, 0);
                acc[n] = __builtin_amdgcn_mfma_f32_16x16x32_bf16(ahi, blo, acc[n], 0, 0, 0);
            }
        }

        // ---- steps 2,3: acc = T x s{2,3}
        #pragma unroll 1
        for (int s = 0; s < 2; ++s) {
            const unsigned short* BB = (s == 0) ? s2 : s3;
            // store T rows (wave-local), then reinit acc
            #pragma unroll
            for (int n = 0; n < 8; ++n)
                #pragma unroll
                for (int rr = 0; rr < 4; ++rr)
                    T[(wave * 16 + lkhi * 4 + rr) * 132 + n * 16 + lrow] = acc[n][rr];
            #pragma unroll
            for (int n = 0; n < 8; ++n) acc[n] = (f32x4){0.f, 0.f, 0.f, 0.f};
            #pragma unroll
            for (int ks = 0; ks < 4; ++ks) {
                const float* tp = &T[(wave * 16 + lrow) * 132 + ks * 32 + lkhi * 8];
                f32x4 a0 = *reinterpret_cast<const f32x4*>(tp);
                f32x4 a1 = *reinterpret_cast<const f32x4*>(tp + 4);
                union { bf16x8 v; unsigned short u[8]; } uh, ul;
                #pragma unroll
                for (int e = 0; e < 4; ++e) {
                    unsigned short h0, l0, h1, l1;
                    bsplit(a0[e], h0, l0);
                    bsplit(a1[e], h1, l1);
                    uh.u[e] = h0;     ul.u[e] = l0;
                    uh.u[e + 4] = h1; ul.u[e + 4] = l1;
                }
                #pragma unroll
                for (int n = 0; n < 8; ++n) {
                    const unsigned short* bp = BB + ((size_t)(n * 4 + ks) * 64 + lane) * 8;
                    bf16x8 bhi = *reinterpret_cast<const bf16x8*>(bp);
                    bf16x8 blo = *reinterpret_cast<const bf16x8*>(bp + MATELEM);
                    acc[n] = __builtin_amdgcn_mfma_f32_16x16x32_bf16(uh.v, bhi, acc[n], 0, 0, 0);
                    acc[n] = __builtin_amdgcn_mfma_f32_16x16x32_bf16(ul.v, bhi, acc[n], 0, 0, 0);
                    acc[n] = __builtin_amdgcn_mfma_f32_16x16x32_bf16(uh.v, blo, acc[n], 0, 0, 0);
                }
            }
        }

        // ---- emit hi/lo planes for this mtile
        if (as_a) {
            #pragma unroll
            for (int n = 0; n < 8; ++n) {
                const int col = n * 16 + lrow;
                #pragma unroll
                for (int rr = 0; rr < 4; ++rr) {
                    unsigned short hi, lo;
                    bsplit(acc[n][rr], hi, lo);
                    const size_t aflat = ((size_t)(mt * 4 + (col >> 5)) * 64 +
                                          ((col >> 3) & 3) * 16 + lkhi * 4 + rr) * 8 + (col & 7);
                    D[aflat]           = hi;
                    D[MATELEM + aflat] = lo;
                }
            }
        } else {
            const int row0 = mt * 16 + lkhi * 4;
            #pragma unroll
            for (int n = 0; n < 8; ++n) {
                u16x4 chi, clo;
                #pragma unroll
                for (int rr = 0; rr < 4; ++rr) {
                    unsigned short hi, lo;
                    bsplit(acc[n][rr], hi, lo);
                    chi[rr] = hi;
                    clo[rr] = lo;
                }
                const size_t bflat = ((size_t)(n * 4 + (row0 >> 5)) * 64 +
                                      ((row0 >> 3) & 3) * 16 + lrow) * 8 + (lkhi & 1) * 4;
                *reinterpret_cast<u16x4*>(D + bflat)           = chi;
                *reinterpret_cast<u16x4*>(D + MATELEM + bflat) = clo;
            }
        }
    }
}

// ---------------------------------------------------------------------------
// Fused kernel. Blocks 0..31: build (block = one 64-row half of one chunk's
// 508-pair scan; then fan4 tree 16->4->1 on blocks 0..3 / 0 with P2P flags).
// Blocks 32..2079: gemm 64 rows each — prefetch x into registers FIRST
// (overlaps with build), then wait on R-ready flag, then MFMA + store.
// Flags: [0..31] scan halves, [40..43] L0, [64] R-ready (own cache line).
// ---------------------------------------------------------------------------
__global__ __launch_bounds__(256) void fused_kernel(
        const float* __restrict__ x,
        const float* __restrict__ theta,
        unsigned short* __restrict__ buf,
        int* __restrict__ flags,
        float* __restrict__ out) {
    __shared__ float lds[9272];   // 37,088 B: scan R[64][129]+cs[508] / fan4 T[64][132]

    const int bid  = blockIdx.x;
    const int t    = threadIdx.x;
    const int lane = t & 63;
    const int wave = t >> 6;
    const int lrow = lane & 15;
    const int lkhi = lane >> 4;

    if (bid >= NBUILDB) {
        // ================= GEMM path =================
        const int g = bid - NBUILDB;
        const long xrow = (long)g * 64 + wave * 16 + lrow;
        const float* xr = x + xrow * DDIM;

        // prefetch x + convert to A-frags (overlaps the R-build)
        bf16x8 afr[4];
        #pragma unroll
        for (int ks = 0; ks < 4; ++ks) {
            f32x4 lo = *reinterpret_cast<const f32x4*>(xr + ks * 32 + lkhi * 8);
            f32x4 hi = *reinterpret_cast<const f32x4*>(xr + ks * 32 + lkhi * 8 + 4);
            union { bf16x8 v; unsigned short u[8]; } ua;
            #pragma unroll
            for (int e = 0; e < 4; ++e) {
                ua.u[e]     = f32_to_bf16_rne(lo[e]);
                ua.u[e + 4] = f32_to_bf16_rne(hi[e]);
            }
            afr[ks] = ua.v;
        }

        if (t == 0) waitflag_slow(flags + 64);
        __syncthreads();
        while (__hip_atomic_load(flags + 64, __ATOMIC_ACQUIRE,
                                 __HIP_MEMORY_SCOPE_AGENT) == 0) {}

        const unsigned short* B = buf + (size_t)SLOT_R * MSTRIDE;   // B_hi plane
        f32x4 acc[8];
        #pragma unroll
        for (int n = 0; n < 8; ++n) acc[n] = (f32x4){0.f, 0.f, 0.f, 0.f};
        #pragma unroll
        for (int ks = 0; ks < 4; ++ks) {
            #pragma unroll
            for (int n = 0; n < 8; ++n) {
                bf16x8 bhi = *reinterpret_cast<const bf16x8*>(
                    B + ((size_t)(n * 4 + ks) * 64 + lane) * 8);
                acc[n] = __builtin_amdgcn_mfma_f32_16x16x32_bf16(afr[ks], bhi, acc[n], 0, 0, 0);
            }
        }
        const long orow0 = (long)g * 64 + wave * 16 + lkhi * 4;
        #pragma unroll
        for (int rr = 0; rr < 4; ++rr) {
            #pragma unroll
            for (int n = 0; n < 8; ++n)
                out[(orow0 + rr) * DDIM + n * 16 + lrow] = acc[n][rr];
        }
        return;
    }

    // ================= BUILD path =================
    const int c = bid >> 1;        // chunk 0..15
    const int h = bid & 1;         // row-half
    const int p0 = c * CPAIRS;
    float2* cs = reinterpret_cast<float2*>(lds + 64 * 129);

    for (int idx = t; idx < CPAIRS; idx += 256) {
        float th = theta[p0 + idx];
        cs[idx] = make_float2(cosf(th), sinf(th));
    }
    if (t < 64) {
        const int grow = h * 64 + t;
        float* row = lds + t * 129;
        for (int q = 0; q < DDIM; ++q) row[q] = (q == grow) ? 1.0f : 0.0f;
    }
    __syncthreads();

    if (t < 64) {
        // locate (i0, j0) for global pair index p0 in triu order
        int i0 = 0, rem = p0;
        while (rem >= DDIM - 1 - i0) { rem -= DDIM - 1 - i0; ++i0; }
        int j0 = i0 + 1 + rem;

        float* row = lds + t * 129;
        int p = 0, ii = i0, jj = j0;
        while (p < CPAIRS) {
            float ri = row[ii];
            const int run = min(DDIM - jj, CPAIRS - p);
            int q = 0;
            for (; q + 8 <= run; q += 8) {          // 8-wide register staging
                float  rj[8];
                float2 aa[8];
                #pragma unroll
                for (int e = 0; e < 8; ++e) { rj[e] = row[jj + q + e]; aa[e] = cs[p + q + e]; }
                #pragma unroll
                for (int e = 0; e < 8; ++e) {
                    row[jj + q + e] = fmaf(aa[e].y, ri, aa[e].x * rj[e]);   // s*xi + c*xj
                    ri              = fmaf(aa[e].x, ri, -(aa[e].y * rj[e])); // c*xi - s*xj
                }
            }
            for (; q < run; ++q) {
                float2 a = cs[p + q];
                float rj = row[jj + q];
                row[jj + q] = fmaf(a.y, ri, a.x * rj);
                ri          = fmaf(a.x, ri, -(a.y * rj));
            }
            row[ii] = ri;
            p += run; ++ii; jj = ii + 1;
        }
    }
    __syncthreads();

    // emit this half's slice of slot c's role planes
    unsigned short* dst = buf + (size_t)c * MSTRIDE;
    if ((c & 3) == 0) {
        // A-role: rows [64h, 64h+64)
        for (int oi = t; oi < 8192; oi += 256) {
            int e = oi & 7, l6 = (oi >> 3) & 63, ks = (oi >> 9) & 3, mtl = oi >> 11;
            int mt  = h * 4 + mtl;
            int lr  = mtl * 16 + (l6 & 15);                  // local row
            int k   = ks * 32 + ((l6 >> 4) << 3) + e;
            unsigned short hi, lo;
            bsplit(lds[lr * 129 + k], hi, lo);
            const size_t aflat = ((size_t)(mt * 4 + ks) * 64 + l6) * 8 + e;
            dst[aflat]           = hi;
            dst[MATELEM + aflat] = lo;
        }
    } else {
        // B-role: k in [64h, 64h+64)
        for (int oi = t; oi < 8192; oi += 256) {
            int e = oi & 7, l6 = (oi >> 3) & 63, ksl = (oi >> 9) & 1, nt = oi >> 10;
            int ks  = 2 * h + ksl;
            int col = nt * 16 + (l6 & 15);
            int lk  = ksl * 32 + ((l6 >> 4) << 3) + e;       // local row (= k - 64h)
            unsigned short hi, lo;
            bsplit(lds[lk * 129 + col], hi, lo);
            const size_t bflat = ((size_t)(nt * 4 + ks) * 64 + l6) * 8 + e;
            dst[bflat]           = hi;
            dst[MATELEM + bflat] = lo;
        }
    }
    __threadfence();
    __syncthreads();
    if (t == 0) setflag(flags + bid);

    // ---- level 0: blocks 0..3 combine slots 4b..4b+3 -> slot 16+b
    if (bid < 4) {
        if (t == 0)
            for (int f = 0; f < 8; ++f) waitflag_fast(flags + 8 * bid + f);
        __syncthreads();
        while (__hip_atomic_load(flags + 8 * bid, __ATOMIC_ACQUIRE,
                                 __HIP_MEMORY_SCOPE_AGENT) == 0) {}
        const unsigned short* s0 = buf + (size_t)(4 * bid)     * MSTRIDE;
        const unsigned short* s1 = buf + (size_t)(4 * bid + 1) * MSTRIDE;
        const unsigned short* s2 = buf + (size_t)(4 * bid + 2) * MSTRIDE;
        const unsigned short* s3 = buf + (size_t)(4 * bid + 3) * MSTRIDE;
        fan4(s0, s1, s2, s3, buf + (size_t)(SLOT_L0 + bid) * MSTRIDE,
             bid == 0, lds);
        __threadfence();
        __syncthreads();
        if (t == 0) setflag(flags + 40 + bid);
    }

    // ---- level 1: block 0 combines slots 16..19 -> slot 20 (B-role, = R)
    if (bid == 0) {
        if (t == 0)
            for (int f = 0; f < 4; ++f) waitflag_fast(flags + 40 + f);
        __syncthreads();
        while (__hip_atomic_load(flags + 40, __ATOMIC_ACQUIRE,
                                 __HIP_MEMORY_SCOPE_AGENT) == 0) {}
        fan4(buf + (size_t)(SLOT_L0 + 0) * MSTRIDE,
             buf + (size_t)(SLOT_L0 + 1) * MSTRIDE,
             buf + (size_t)(SLOT_L0 + 2) * MSTRIDE,
             buf + (size_t)(SLOT_L0 + 3) * MSTRIDE,
             buf + (size_t)SLOT_R * MSTRIDE, false, lds);
        __threadfence();
        __syncthreads();
        if (t == 0) setflag(flags + 64);
    }
}

extern "C" void kernel_launch(void* const* d_in, const int* in_sizes, int n_in,
                              void* d_out, int out_size, void* d_ws, size_t ws_size,
                              hipStream_t stream) {
    (void)in_sizes; (void)n_in; (void)out_size; (void)ws_size;
    const float* x     = (const float*)d_in[0];
    const float* theta = (const float*)d_in[1];
    // d_in[2] (pairs) is deterministic triu_indices(128,1) order; derived on device.
    float* out = (float*)d_out;

    // ws: 21 slots x 2 planes x 16384 bf16 = 1.31 MB; flags at +4 MB.
    unsigned short* buf   = (unsigned short*)d_ws;
    int*            flags = (int*)((char*)d_ws + (1 << 22));

    hipMemsetAsync(flags, 0, 512, stream);
    fused_kernel<<<NBUILDB + NGEMMB, 256, 0, stream>>>(x, theta, buf, flags, out);
}